// Round 1
// baseline (5139.318 us; speedup 1.0000x reference)
//
#include <hip/hip_runtime.h>
#include <hip/hip_bf16.h>
#include <cstdint>

#define T_STEPS 24

__device__ __forceinline__ float bcast(float v, int lane) {
    return __int_as_float(__builtin_amdgcn_readlane(__float_as_int(v), lane));
}
__device__ __forceinline__ float sigm(float x) {
    return 1.f / (1.f + __expf(-x));
}
__device__ __forceinline__ float tanh_(float x) {
    float t = __expf(2.f * x);
    return 1.f - 2.f / (t + 1.f);
}
__device__ __forceinline__ unsigned fkey(float f) {
    unsigned u = __float_as_uint(f);
    return (u & 0x80000000u) ? ~u : (u | 0x80000000u);
}
__device__ __forceinline__ float fdecode(unsigned k) {
    unsigned u = (k & 0x80000000u) ? (k ^ 0x80000000u) : ~k;
    return __uint_as_float(u);
}

// ---------------- LSTM: one wave handles 2 nodes; lane j owns channel j ----
__global__ void lstm_kernel(const float* __restrict__ x,
                            const float* __restrict__ W_ih,
                            const float* __restrict__ W_hh,
                            const float* __restrict__ b_ih,
                            const float* __restrict__ b_hh,
                            float* __restrict__ h_out,
                            float* __restrict__ fc1acc,
                            int N) {
    __shared__ float Wp[64 * 64 * 4];  // [k][j][gate]
    int tid = threadIdx.x;
    for (int i = tid; i < 64 * 64 * 4; i += 256) {
        int k = i >> 8, j = (i >> 2) & 63, g = i & 3;
        Wp[i] = W_hh[(g * 64 + j) * 64 + k];
    }
    __syncthreads();
    int lane = tid & 63;
    int wave = tid >> 6;
    int wgid = blockIdx.x * 4 + wave;
    int nA = wgid * 2, nB = nA + 1;
    bool hasA = nA < N, hasB = nB < N;

    float wih[4][2], bc4[4];
#pragma unroll
    for (int g = 0; g < 4; ++g) {
        int r = g * 64 + lane;
        wih[g][0] = W_ih[r * 2 + 0];
        wih[g][1] = W_ih[r * 2 + 1];
        bc4[g] = b_ih[r] + b_hh[r];
    }
    float xa0 = 0, xa1 = 0, xb0 = 0, xb1 = 0;
    if (lane < T_STEPS) {
        if (hasA) { xa0 = x[(nA * T_STEPS + lane) * 2 + 0]; xa1 = x[(nA * T_STEPS + lane) * 2 + 1]; }
        if (hasB) { xb0 = x[(nB * T_STEPS + lane) * 2 + 0]; xb1 = x[(nB * T_STEPS + lane) * 2 + 1]; }
    }
    float hA = 0, cA = 0, hB = 0, cB = 0;
    for (int t = 0; t < T_STEPS; ++t) {
        float x0A = bcast(xa0, t), x1A = bcast(xa1, t);
        float x0B = bcast(xb0, t), x1B = bcast(xb1, t);
        float aA[4], aB[4];
#pragma unroll
        for (int g = 0; g < 4; ++g) {
            aA[g] = bc4[g] + wih[g][0] * x0A + wih[g][1] * x1A;
            aB[g] = bc4[g] + wih[g][0] * x0B + wih[g][1] * x1B;
        }
#pragma unroll 8
        for (int k = 0; k < 64; ++k) {
            float4 w = *reinterpret_cast<const float4*>(&Wp[(k * 64 + lane) * 4]);
            float hkA = bcast(hA, k);
            float hkB = bcast(hB, k);
            aA[0] += w.x * hkA; aA[1] += w.y * hkA; aA[2] += w.z * hkA; aA[3] += w.w * hkA;
            aB[0] += w.x * hkB; aB[1] += w.y * hkB; aB[2] += w.z * hkB; aB[3] += w.w * hkB;
        }
        cA = sigm(aA[1]) * cA + sigm(aA[0]) * tanh_(aA[2]);
        hA = sigm(aA[3]) * tanh_(cA);
        cB = sigm(aB[1]) * cB + sigm(aB[0]) * tanh_(aB[2]);
        hB = sigm(aB[3]) * tanh_(cB);
    }
    if (hasA) { h_out[nA * 64 + lane] = hA; fc1acc[nA * 64 + lane] = 0.f; }
    if (hasB) { h_out[nB * 64 + lane] = hB; fc1acc[nB * 64 + lane] = 0.f; }
}

// ---------------- GAT per-node: hs = h@W, asrc/adst scores, we_ae ----------
__global__ void gat_scores_kernel(const float* __restrict__ h,
                                  const float* __restrict__ Wg,
                                  const float* __restrict__ a_s,
                                  const float* __restrict__ a_d,
                                  const float* __restrict__ W_e,
                                  const float* __restrict__ a_e,
                                  float* __restrict__ hs,
                                  float* __restrict__ asrc,
                                  float* __restrict__ adst,
                                  float* __restrict__ weae,
                                  int N) {
    __shared__ float Wl[64 * 64];  // [k][j]
    int tid = threadIdx.x;
    for (int i = tid; i < 4096; i += 256) Wl[i] = Wg[i];
    __syncthreads();
    if (blockIdx.x == 0 && tid < 2) {
        float s = 0;
        for (int j = 0; j < 64; ++j) s += W_e[tid * 64 + j] * a_e[j];
        weae[tid] = s;
    }
    int lane = tid & 63, wave = tid >> 6;
    int n = blockIdx.x * 4 + wave;
    if (n >= N) return;
    float hv = h[n * 64 + lane];
    float acc = 0.f;
#pragma unroll 8
    for (int k = 0; k < 64; ++k) acc += bcast(hv, k) * Wl[k * 64 + lane];
    hs[n * 64 + lane] = acc;
    float ps = acc * a_s[lane];
    float pd = acc * a_d[lane];
    for (int m = 32; m; m >>= 1) { ps += __shfl_xor(ps, m, 64); pd += __shfl_xor(pd, m, 64); }
    if (lane == 0) { asrc[n] = ps; adst[n] = pd; }
}

__global__ void layer_init_kernel(float* __restrict__ go, const float* __restrict__ bias,
                                  float* __restrict__ den, unsigned* __restrict__ amax,
                                  double* __restrict__ stats, int N) {
    int i = blockIdx.x * blockDim.x + threadIdx.x;
    if (i < N * 64) {
        go[i] = bias[i & 63];
        if ((i & 63) == 0) { den[i >> 6] = 0.f; amax[i >> 6] = 0u; }
    }
    if (i == 0) { stats[0] = 0.0; stats[1] = 0.0; }
}

__global__ void edge_alpha_kernel(const int* __restrict__ ei, const float* __restrict__ ea,
                                  const float* __restrict__ asrc, const float* __restrict__ adst,
                                  const float* __restrict__ weae, float* __restrict__ alpha,
                                  unsigned* __restrict__ amax, int E) {
    int e = blockIdx.x * blockDim.x + threadIdx.x;
    if (e >= E) return;
    int s = ei[e], d = ei[E + e];
    float a = asrc[s] + adst[d] + ea[e * 2 + 0] * weae[0] + ea[e * 2 + 1] * weae[1];
    a = a > 0.f ? a : 0.2f * a;
    alpha[e] = a;
    atomicMax(&amax[d], fkey(a));
}

__global__ void edge_exp_kernel(const int* __restrict__ ei, float* __restrict__ alpha,
                                const unsigned* __restrict__ amax, float* __restrict__ den,
                                int E) {
    int e = blockIdx.x * blockDim.x + threadIdx.x;
    if (e >= E) return;
    int d = ei[E + e];
    float ex = __expf(alpha[e] - fdecode(amax[d]));
    alpha[e] = ex;
    unsafeAtomicAdd(&den[d], ex);
}

__global__ void edge_message_kernel(const int* __restrict__ ei, const float* __restrict__ hs,
                                    const float* __restrict__ alpha, const float* __restrict__ den,
                                    float* __restrict__ go, int E) {
    int wid = (int)((blockIdx.x * (unsigned)blockDim.x + threadIdx.x) >> 6);
    int lane = threadIdx.x & 63;
    if (wid >= E) return;
    int s = ei[wid], d = ei[E + wid];
    float w = alpha[wid] / (den[d] + 1e-16f);
    unsafeAtomicAdd(&go[d * 64 + lane], hs[s * 64 + lane] * w);
}

__global__ void ln_stats_kernel(const float* __restrict__ go, double* __restrict__ stats, int M) {
    double s = 0, ss = 0;
    for (int i = blockIdx.x * blockDim.x + threadIdx.x; i < M; i += gridDim.x * blockDim.x) {
        float v = go[i];
        s += v; ss += (double)v * v;
    }
    for (int m = 32; m; m >>= 1) { s += __shfl_xor(s, m, 64); ss += __shfl_xor(ss, m, 64); }
    __shared__ double sh[8];
    int wave = threadIdx.x >> 6, lane = threadIdx.x & 63;
    if (lane == 0) { sh[wave * 2] = s; sh[wave * 2 + 1] = ss; }
    __syncthreads();
    if (threadIdx.x == 0) {
        double ts = 0, tss = 0;
        for (int w2 = 0; w2 < 4; ++w2) { ts += sh[w2 * 2]; tss += sh[w2 * 2 + 1]; }
        unsafeAtomicAdd(&stats[0], ts);
        unsafeAtomicAdd(&stats[1], tss);
    }
}

// LN(graph) + ReLU -> h, and fc1acc += relu_out @ W_fc1_slice^T (JK fused)
__global__ void ln_apply_kernel(const float* __restrict__ go, const double* __restrict__ stats,
                                const float* __restrict__ g, const float* __restrict__ b,
                                const float* __restrict__ W_fc1, int lofs,
                                float* __restrict__ h, float* __restrict__ fc1acc, int N) {
    __shared__ float Wl[64 * 64];  // [k][o]
    int tid = threadIdx.x;
    for (int i = tid; i < 4096; i += 256) {
        int k = i >> 6, o = i & 63;
        Wl[i] = W_fc1[o * 320 + lofs + k];
    }
    __syncthreads();
    double M = (double)N * 64.0;
    double mu = stats[0] / M;
    float mean = (float)mu;
    float var = (float)(stats[1] / M - mu * mu);
    float inv = 1.f / (sqrtf(fmaxf(var, 0.f)) + 1e-5f);
    int lane = tid & 63, wave = tid >> 6;
    int n = blockIdx.x * 4 + wave;
    if (n >= N) return;
    float v = (go[n * 64 + lane] - mean) * inv * g[lane] + b[lane];
    v = fmaxf(v, 0.f);
    h[n * 64 + lane] = v;
    float acc = 0.f;
#pragma unroll 8
    for (int k = 0; k < 64; ++k) acc += bcast(v, k) * Wl[k * 64 + lane];
    fc1acc[n * 64 + lane] += acc;
}

__global__ void head_kernel(const float* __restrict__ fc1acc, const float* __restrict__ b1,
                            const float* __restrict__ W2, const float* __restrict__ b2,
                            float* __restrict__ out, int N) {
    int lane = threadIdx.x & 63, wave = threadIdx.x >> 6;
    int n = blockIdx.x * 4 + wave;
    if (n >= N) return;
    float v = fmaxf(fc1acc[n * 64 + lane] + b1[lane], 0.f);
    float r0 = v * W2[lane];
    float r1 = v * W2[64 + lane];
    for (int m = 32; m; m >>= 1) { r0 += __shfl_xor(r0, m, 64); r1 += __shfl_xor(r1, m, 64); }
    if (lane == 0) { out[n * 2 + 0] = r0 + b2[0]; out[n * 2 + 1] = r1 + b2[1]; }
}

extern "C" void kernel_launch(void* const* d_in, const int* in_sizes, int n_in,
                              void* d_out, int out_size, void* d_ws, size_t ws_size,
                              hipStream_t stream) {
    const float* x        = (const float*)d_in[0];
    const int*   ei       = (const int*)d_in[1];
    const float* ea       = (const float*)d_in[2];
    const float* W_ih     = (const float*)d_in[3];
    const float* W_hh     = (const float*)d_in[4];
    const float* b_ih     = (const float*)d_in[5];
    const float* b_hh     = (const float*)d_in[6];
    const float* W_gat    = (const float*)d_in[7];
    const float* att_src  = (const float*)d_in[8];
    const float* att_dst  = (const float*)d_in[9];
    const float* W_edge   = (const float*)d_in[10];
    const float* att_edge = (const float*)d_in[11];
    const float* b_gat    = (const float*)d_in[12];
    const float* ln_g     = (const float*)d_in[13];
    const float* ln_b     = (const float*)d_in[14];
    const float* W_fc1    = (const float*)d_in[15];
    const float* b_fc1    = (const float*)d_in[16];
    const float* W_fc2    = (const float*)d_in[17];
    const float* b_fc2    = (const float*)d_in[18];
    float* out = (float*)d_out;

    int N = in_sizes[0] / (T_STEPS * 2);
    int E = in_sizes[1] / 2;
    size_t N64 = (size_t)N * 64;

    float* ws   = (float*)d_ws;
    float* h    = ws;
    float* hs   = h + N64;
    float* go   = hs + N64;
    float* fc1  = go + N64;
    float* asrc = fc1 + N64;
    float* adst = asrc + N;
    unsigned* amax = (unsigned*)(adst + N);
    float* den  = (float*)(amax + N);
    float* alpha = den + N;
    float* weae  = alpha + E;
    double* stats = (double*)(((uintptr_t)(weae + 2) + 15) & ~(uintptr_t)15);

    lstm_kernel<<<(N + 7) / 8, 256, 0, stream>>>(x, W_ih, W_hh, b_ih, b_hh, h, fc1, N);
    for (int l = 0; l < 5; ++l) {
        gat_scores_kernel<<<(N + 3) / 4, 256, 0, stream>>>(
            h, W_gat + l * 4096, att_src + l * 64, att_dst + l * 64,
            W_edge + l * 128, att_edge + l * 64, hs, asrc, adst, weae, N);
        layer_init_kernel<<<(N * 64 + 255) / 256, 256, 0, stream>>>(go, b_gat + l * 64, den, amax, stats, N);
        edge_alpha_kernel<<<(E + 255) / 256, 256, 0, stream>>>(ei, ea, asrc, adst, weae, alpha, amax, E);
        edge_exp_kernel<<<(E + 255) / 256, 256, 0, stream>>>(ei, alpha, amax, den, E);
        edge_message_kernel<<<(E + 3) / 4, 256, 0, stream>>>(ei, hs, alpha, den, go, E);
        ln_stats_kernel<<<2048, 256, 0, stream>>>(go, stats, N * 64);
        ln_apply_kernel<<<(N + 3) / 4, 256, 0, stream>>>(go, stats, ln_g + l * 64, ln_b + l * 64,
                                                         W_fc1, l * 64, h, fc1, N);
    }
    head_kernel<<<(N + 3) / 4, 256, 0, stream>>>(fc1, b_fc1, W_fc2, b_fc2, out, N);
}

// Round 2
// 4291.656 us; speedup vs baseline: 1.1975x; 1.1975x over previous
//
#include <hip/hip_runtime.h>
#include <hip/hip_bf16.h>
#include <cstdint>

#define T_STEPS 24

__device__ __forceinline__ float bcast(float v, int lane) {
    return __int_as_float(__builtin_amdgcn_readlane(__float_as_int(v), lane));
}
__device__ __forceinline__ float sigm(float x) {
    return 1.f / (1.f + __expf(-x));
}
__device__ __forceinline__ float tanh_(float x) {
    float t = __expf(2.f * x);
    return 1.f - 2.f / (t + 1.f);
}
__device__ __forceinline__ unsigned fkey(float f) {
    unsigned u = __float_as_uint(f);
    return (u & 0x80000000u) ? ~u : (u | 0x80000000u);
}
__device__ __forceinline__ float fdecode(unsigned k) {
    unsigned u = (k & 0x80000000u) ? (k ^ 0x80000000u) : ~k;
    return __uint_as_float(u);
}

// ---- LSTM: 1024-thread block (16 waves share 64KB W_hh LDS), 4 nodes/wave.
// 2 blocks/CU -> 32 waves/CU occupancy; per k: 1 ds_read_b128 + 4 readlane
// + 16 FMA.
__global__ __launch_bounds__(1024, 8) void lstm_kernel(
        const float* __restrict__ x,
        const float* __restrict__ W_ih,
        const float* __restrict__ W_hh,
        const float* __restrict__ b_ih,
        const float* __restrict__ b_hh,
        float* __restrict__ h_out,
        float* __restrict__ fc1acc,
        int N) {
    __shared__ float Wp[64 * 64 * 4];  // [k][j][gate]
    int tid = threadIdx.x;
    for (int i = tid; i < 64 * 64 * 4; i += 1024) {
        int k = i >> 8, j = (i >> 2) & 63, g = i & 3;
        Wp[i] = W_hh[(g * 64 + j) * 64 + k];
    }
    __syncthreads();
    int lane = tid & 63;
    int wave = tid >> 6;
    int n0 = (blockIdx.x * 16 + wave) * 4;

    float wih0[4], wih1[4], bc4[4];
#pragma unroll
    for (int g = 0; g < 4; ++g) {
        int r = g * 64 + lane;
        wih0[g] = W_ih[r * 2 + 0];
        wih1[g] = W_ih[r * 2 + 1];
        bc4[g] = b_ih[r] + b_hh[r];
    }
    float xs[4][2] = {};
#pragma unroll
    for (int i = 0; i < 4; ++i) {
        if (lane < T_STEPS && n0 + i < N) {
            float2 v = *reinterpret_cast<const float2*>(&x[((n0 + i) * T_STEPS + lane) * 2]);
            xs[i][0] = v.x; xs[i][1] = v.y;
        }
    }
    float h4[4] = {0.f, 0.f, 0.f, 0.f}, c4[4] = {0.f, 0.f, 0.f, 0.f};
    const float4* wp = reinterpret_cast<const float4*>(Wp) + lane;
    for (int t = 0; t < T_STEPS; ++t) {
        float a[4][4];
#pragma unroll
        for (int i = 0; i < 4; ++i) {
            float x0 = bcast(xs[i][0], t), x1 = bcast(xs[i][1], t);
#pragma unroll
            for (int g = 0; g < 4; ++g) a[i][g] = bc4[g] + wih0[g] * x0 + wih1[g] * x1;
        }
#pragma unroll 4
        for (int k = 0; k < 64; ++k) {
            float4 w = wp[k * 64];
#pragma unroll
            for (int i = 0; i < 4; ++i) {
                float hk = bcast(h4[i], k);
                a[i][0] += w.x * hk; a[i][1] += w.y * hk;
                a[i][2] += w.z * hk; a[i][3] += w.w * hk;
            }
        }
#pragma unroll
        for (int i = 0; i < 4; ++i) {
            c4[i] = sigm(a[i][1]) * c4[i] + sigm(a[i][0]) * tanh_(a[i][2]);
            h4[i] = sigm(a[i][3]) * tanh_(c4[i]);
        }
    }
#pragma unroll
    for (int i = 0; i < 4; ++i) {
        if (n0 + i < N) {
            h_out[(n0 + i) * 64 + lane] = h4[i];
            fc1acc[(n0 + i) * 64 + lane] = 0.f;
        }
    }
}

// ---------------- GAT per-node: hs = h@W, asrc/adst scores, we_ae ----------
// 4 nodes per wave.
__global__ void gat_scores_kernel(const float* __restrict__ h,
                                  const float* __restrict__ Wg,
                                  const float* __restrict__ a_s,
                                  const float* __restrict__ a_d,
                                  const float* __restrict__ W_e,
                                  const float* __restrict__ a_e,
                                  float* __restrict__ hs,
                                  float* __restrict__ asrc,
                                  float* __restrict__ adst,
                                  float* __restrict__ weae,
                                  int N) {
    __shared__ float Wl[64 * 64];  // [k][j]
    int tid = threadIdx.x;
    for (int i = tid; i < 4096; i += 256) Wl[i] = Wg[i];
    __syncthreads();
    if (blockIdx.x == 0 && tid < 2) {
        float s = 0;
        for (int j = 0; j < 64; ++j) s += W_e[tid * 64 + j] * a_e[j];
        weae[tid] = s;
    }
    int lane = tid & 63, wave = tid >> 6;
    int n0 = (blockIdx.x * 4 + wave) * 4;
    if (n0 >= N) return;
    float hv[4], acc[4] = {};
#pragma unroll
    for (int i = 0; i < 4; ++i) hv[i] = (n0 + i < N) ? h[(n0 + i) * 64 + lane] : 0.f;
#pragma unroll 4
    for (int k = 0; k < 64; ++k) {
        float w = Wl[k * 64 + lane];
#pragma unroll
        for (int i = 0; i < 4; ++i) acc[i] += bcast(hv[i], k) * w;
    }
    float as = a_s[lane], ad = a_d[lane];
#pragma unroll
    for (int i = 0; i < 4; ++i) {
        if (n0 + i >= N) break;
        hs[(n0 + i) * 64 + lane] = acc[i];
        float ps = acc[i] * as;
        float pd = acc[i] * ad;
        for (int m = 32; m; m >>= 1) { ps += __shfl_xor(ps, m, 64); pd += __shfl_xor(pd, m, 64); }
        if (lane == 0) { asrc[n0 + i] = ps; adst[n0 + i] = pd; }
    }
}

__global__ void layer_init_kernel(float* __restrict__ go, const float* __restrict__ bias,
                                  float* __restrict__ den, unsigned* __restrict__ amax,
                                  double* __restrict__ stats, int N) {
    int i = blockIdx.x * blockDim.x + threadIdx.x;
    if (i < N * 64) {
        go[i] = bias[i & 63];
        if ((i & 63) == 0) { den[i >> 6] = 0.f; amax[i >> 6] = 0u; }
    }
    if (i == 0) { stats[0] = 0.0; stats[1] = 0.0; }
}

__global__ void edge_alpha_kernel(const int* __restrict__ ei, const float* __restrict__ ea,
                                  const float* __restrict__ asrc, const float* __restrict__ adst,
                                  const float* __restrict__ weae, float* __restrict__ alpha,
                                  unsigned* __restrict__ amax, int E) {
    int e = blockIdx.x * blockDim.x + threadIdx.x;
    if (e >= E) return;
    int s = ei[e], d = ei[E + e];
    float2 eav = *reinterpret_cast<const float2*>(&ea[e * 2]);
    float a = asrc[s] + adst[d] + eav.x * weae[0] + eav.y * weae[1];
    a = a > 0.f ? a : 0.2f * a;
    alpha[e] = a;
    atomicMax(&amax[d], fkey(a));
}

__global__ void edge_exp_kernel(const int* __restrict__ ei, float* __restrict__ alpha,
                                const unsigned* __restrict__ amax, float* __restrict__ den,
                                int E) {
    int e = blockIdx.x * blockDim.x + threadIdx.x;
    if (e >= E) return;
    int d = ei[E + e];
    float ex = __expf(alpha[e] - fdecode(amax[d]));
    alpha[e] = ex;
    unsafeAtomicAdd(&den[d], ex);
}

__global__ void edge_message_kernel(const int* __restrict__ ei, const float* __restrict__ hs,
                                    const float* __restrict__ alpha, const float* __restrict__ den,
                                    float* __restrict__ go, int E) {
    int wid = (int)((blockIdx.x * (unsigned)blockDim.x + threadIdx.x) >> 6);
    int lane = threadIdx.x & 63;
    if (wid >= E) return;
    int s = ei[wid], d = ei[E + wid];
    float w = alpha[wid] / (den[d] + 1e-16f);
    unsafeAtomicAdd(&go[d * 64 + lane], hs[s * 64 + lane] * w);
}

__global__ void ln_stats_kernel(const float* __restrict__ go, double* __restrict__ stats, int M) {
    double s = 0, ss = 0;
    for (int i = blockIdx.x * blockDim.x + threadIdx.x; i < M; i += gridDim.x * blockDim.x) {
        float v = go[i];
        s += v; ss += (double)v * v;
    }
    for (int m = 32; m; m >>= 1) { s += __shfl_xor(s, m, 64); ss += __shfl_xor(ss, m, 64); }
    __shared__ double sh[8];
    int wave = threadIdx.x >> 6, lane = threadIdx.x & 63;
    if (lane == 0) { sh[wave * 2] = s; sh[wave * 2 + 1] = ss; }
    __syncthreads();
    if (threadIdx.x == 0) {
        double ts = 0, tss = 0;
        for (int w2 = 0; w2 < 4; ++w2) { ts += sh[w2 * 2]; tss += sh[w2 * 2 + 1]; }
        unsafeAtomicAdd(&stats[0], ts);
        unsafeAtomicAdd(&stats[1], tss);
    }
}

// LN(graph) + ReLU -> h, and fc1acc += relu_out @ W_fc1_slice^T (JK fused)
// 4 nodes per wave.
__global__ void ln_apply_kernel(const float* __restrict__ go, const double* __restrict__ stats,
                                const float* __restrict__ g, const float* __restrict__ b,
                                const float* __restrict__ W_fc1, int lofs,
                                float* __restrict__ h, float* __restrict__ fc1acc, int N) {
    __shared__ float Wl[64 * 64];  // [k][o]
    int tid = threadIdx.x;
    for (int i = tid; i < 4096; i += 256) {
        int k = i >> 6, o = i & 63;
        Wl[i] = W_fc1[o * 320 + lofs + k];
    }
    __syncthreads();
    double M = (double)N * 64.0;
    double mu = stats[0] / M;
    float mean = (float)mu;
    float var = (float)(stats[1] / M - mu * mu);
    float inv = 1.f / (sqrtf(fmaxf(var, 0.f)) + 1e-5f);
    int lane = tid & 63, wave = tid >> 6;
    int n0 = (blockIdx.x * 4 + wave) * 4;
    if (n0 >= N) return;
    float gl = g[lane], bl = b[lane];
    float v[4], acc[4] = {};
#pragma unroll
    for (int i = 0; i < 4; ++i) {
        float t = (n0 + i < N) ? go[(n0 + i) * 64 + lane] : 0.f;
        v[i] = fmaxf((t - mean) * inv * gl + bl, 0.f);
    }
#pragma unroll 4
    for (int k = 0; k < 64; ++k) {
        float w = Wl[k * 64 + lane];
#pragma unroll
        for (int i = 0; i < 4; ++i) acc[i] += bcast(v[i], k) * w;
    }
#pragma unroll
    for (int i = 0; i < 4; ++i) {
        if (n0 + i >= N) break;
        h[(n0 + i) * 64 + lane] = v[i];
        fc1acc[(n0 + i) * 64 + lane] += acc[i];
    }
}

__global__ void head_kernel(const float* __restrict__ fc1acc, const float* __restrict__ b1,
                            const float* __restrict__ W2, const float* __restrict__ b2,
                            float* __restrict__ out, int N) {
    int lane = threadIdx.x & 63, wave = threadIdx.x >> 6;
    int n = blockIdx.x * 4 + wave;
    if (n >= N) return;
    float v = fmaxf(fc1acc[n * 64 + lane] + b1[lane], 0.f);
    float r0 = v * W2[lane];
    float r1 = v * W2[64 + lane];
    for (int m = 32; m; m >>= 1) { r0 += __shfl_xor(r0, m, 64); r1 += __shfl_xor(r1, m, 64); }
    if (lane == 0) { out[n * 2 + 0] = r0 + b2[0]; out[n * 2 + 1] = r1 + b2[1]; }
}

extern "C" void kernel_launch(void* const* d_in, const int* in_sizes, int n_in,
                              void* d_out, int out_size, void* d_ws, size_t ws_size,
                              hipStream_t stream) {
    const float* x        = (const float*)d_in[0];
    const int*   ei       = (const int*)d_in[1];
    const float* ea       = (const float*)d_in[2];
    const float* W_ih     = (const float*)d_in[3];
    const float* W_hh     = (const float*)d_in[4];
    const float* b_ih     = (const float*)d_in[5];
    const float* b_hh     = (const float*)d_in[6];
    const float* W_gat    = (const float*)d_in[7];
    const float* att_src  = (const float*)d_in[8];
    const float* att_dst  = (const float*)d_in[9];
    const float* W_edge   = (const float*)d_in[10];
    const float* att_edge = (const float*)d_in[11];
    const float* b_gat    = (const float*)d_in[12];
    const float* ln_g     = (const float*)d_in[13];
    const float* ln_b     = (const float*)d_in[14];
    const float* W_fc1    = (const float*)d_in[15];
    const float* b_fc1    = (const float*)d_in[16];
    const float* W_fc2    = (const float*)d_in[17];
    const float* b_fc2    = (const float*)d_in[18];
    float* out = (float*)d_out;

    int N = in_sizes[0] / (T_STEPS * 2);
    int E = in_sizes[1] / 2;
    size_t N64 = (size_t)N * 64;

    float* ws   = (float*)d_ws;
    float* h    = ws;
    float* hs   = h + N64;
    float* go   = hs + N64;
    float* fc1  = go + N64;
    float* asrc = fc1 + N64;
    float* adst = asrc + N;
    unsigned* amax = (unsigned*)(adst + N);
    float* den  = (float*)(amax + N);
    float* alpha = den + N;
    float* weae  = alpha + E;
    double* stats = (double*)(((uintptr_t)(weae + 2) + 15) & ~(uintptr_t)15);

    lstm_kernel<<<(N + 63) / 64, 1024, 0, stream>>>(x, W_ih, W_hh, b_ih, b_hh, h, fc1, N);
    for (int l = 0; l < 5; ++l) {
        gat_scores_kernel<<<(N + 15) / 16, 256, 0, stream>>>(
            h, W_gat + l * 4096, att_src + l * 64, att_dst + l * 64,
            W_edge + l * 128, att_edge + l * 64, hs, asrc, adst, weae, N);
        layer_init_kernel<<<(N * 64 + 255) / 256, 256, 0, stream>>>(go, b_gat + l * 64, den, amax, stats, N);
        edge_alpha_kernel<<<(E + 255) / 256, 256, 0, stream>>>(ei, ea, asrc, adst, weae, alpha, amax, E);
        edge_exp_kernel<<<(E + 255) / 256, 256, 0, stream>>>(ei, alpha, amax, den, E);
        edge_message_kernel<<<(E + 3) / 4, 256, 0, stream>>>(ei, hs, alpha, den, go, E);
        ln_stats_kernel<<<2048, 256, 0, stream>>>(go, stats, N * 64);
        ln_apply_kernel<<<(N + 15) / 16, 256, 0, stream>>>(go, stats, ln_g + l * 64, ln_b + l * 64,
                                                           W_fc1, l * 64, h, fc1, N);
    }
    head_kernel<<<(N + 3) / 4, 256, 0, stream>>>(fc1, b_fc1, W_fc2, b_fc2, out, N);
}

// Round 3
// 4283.844 us; speedup vs baseline: 1.1997x; 1.0018x over previous
//
#include <hip/hip_runtime.h>
#include <hip/hip_bf16.h>
#include <cstdint>

#define T_STEPS 24

__device__ __forceinline__ float bcast(float v, int lane) {
    return __int_as_float(__builtin_amdgcn_readlane(__float_as_int(v), lane));
}
__device__ __forceinline__ float sigm(float x) {
    return 1.f / (1.f + __expf(-x));
}
__device__ __forceinline__ float tanh_(float x) {
    float t = __expf(2.f * x);
    return 1.f - 2.f / (t + 1.f);
}
__device__ __forceinline__ unsigned fkey(float f) {
    unsigned u = __float_as_uint(f);
    return (u & 0x80000000u) ? ~u : (u | 0x80000000u);
}
__device__ __forceinline__ float fdecode(unsigned k) {
    unsigned u = (k & 0x80000000u) ? (k ^ 0x80000000u) : ~k;
    return __uint_as_float(u);
}

// ---- LSTM: 512-thread block (8 waves share 64KB W_hh LDS), 8 nodes/wave.
// launch_bounds(512,4) -> 128 VGPR cap so the ~88 live floats fit w/o spills.
// Per k: 1 ds_read_b128 + 8 readlane + 32 FMA (FMA fraction 32/41).
__global__ __launch_bounds__(512, 4) void lstm_kernel(
        const float* __restrict__ x,
        const float* __restrict__ W_ih,
        const float* __restrict__ W_hh,
        const float* __restrict__ b_ih,
        const float* __restrict__ b_hh,
        float* __restrict__ h_out,
        float* __restrict__ fc1acc,
        int N) {
    __shared__ float Wp[64 * 64 * 4];  // [k][j][gate]
    int tid = threadIdx.x;
    for (int i = tid; i < 64 * 64 * 4; i += 512) {
        int k = i >> 8, j = (i >> 2) & 63, g = i & 3;
        Wp[i] = W_hh[(g * 64 + j) * 64 + k];
    }
    __syncthreads();
    int lane = tid & 63;
    int wave = tid >> 6;
    int n0 = (blockIdx.x * 8 + wave) * 8;

    float wih0[4], wih1[4], bc4[4];
#pragma unroll
    for (int g = 0; g < 4; ++g) {
        int r = g * 64 + lane;
        wih0[g] = W_ih[r * 2 + 0];
        wih1[g] = W_ih[r * 2 + 1];
        bc4[g] = b_ih[r] + b_hh[r];
    }
    float xs0[8], xs1[8];
#pragma unroll
    for (int i = 0; i < 8; ++i) {
        xs0[i] = 0.f; xs1[i] = 0.f;
        if (lane < T_STEPS && n0 + i < N) {
            float2 v = *reinterpret_cast<const float2*>(&x[((n0 + i) * T_STEPS + lane) * 2]);
            xs0[i] = v.x; xs1[i] = v.y;
        }
    }
    float h8[8] = {}, c8[8] = {};
    const float4* wp = reinterpret_cast<const float4*>(Wp) + lane;
    for (int t = 0; t < T_STEPS; ++t) {
        float a[8][4];
#pragma unroll
        for (int i = 0; i < 8; ++i) {
            float x0 = bcast(xs0[i], t), x1 = bcast(xs1[i], t);
#pragma unroll
            for (int g = 0; g < 4; ++g) a[i][g] = bc4[g] + wih0[g] * x0 + wih1[g] * x1;
        }
#pragma unroll 2
        for (int k = 0; k < 64; ++k) {
            float4 w = wp[k * 64];
#pragma unroll
            for (int i = 0; i < 8; ++i) {
                float hk = bcast(h8[i], k);
                a[i][0] += w.x * hk; a[i][1] += w.y * hk;
                a[i][2] += w.z * hk; a[i][3] += w.w * hk;
            }
        }
#pragma unroll
        for (int i = 0; i < 8; ++i) {
            c8[i] = sigm(a[i][1]) * c8[i] + sigm(a[i][0]) * tanh_(a[i][2]);
            h8[i] = sigm(a[i][3]) * tanh_(c8[i]);
        }
    }
#pragma unroll
    for (int i = 0; i < 8; ++i) {
        if (n0 + i < N) {
            h_out[(n0 + i) * 64 + lane] = h8[i];
            fc1acc[(n0 + i) * 64 + lane] = 0.f;
        }
    }
}

// ---------------- GAT per-node: hs = h@W, asrc/adst scores, we_ae ----------
// 4 nodes per wave.
__global__ void gat_scores_kernel(const float* __restrict__ h,
                                  const float* __restrict__ Wg,
                                  const float* __restrict__ a_s,
                                  const float* __restrict__ a_d,
                                  const float* __restrict__ W_e,
                                  const float* __restrict__ a_e,
                                  float* __restrict__ hs,
                                  float* __restrict__ asrc,
                                  float* __restrict__ adst,
                                  float* __restrict__ weae,
                                  int N) {
    __shared__ float Wl[64 * 64];  // [k][j]
    int tid = threadIdx.x;
    for (int i = tid; i < 4096; i += 256) Wl[i] = Wg[i];
    __syncthreads();
    if (blockIdx.x == 0 && tid < 2) {
        float s = 0;
        for (int j = 0; j < 64; ++j) s += W_e[tid * 64 + j] * a_e[j];
        weae[tid] = s;
    }
    int lane = tid & 63, wave = tid >> 6;
    int n0 = (blockIdx.x * 4 + wave) * 4;
    if (n0 >= N) return;
    float hv[4], acc[4] = {};
#pragma unroll
    for (int i = 0; i < 4; ++i) hv[i] = (n0 + i < N) ? h[(n0 + i) * 64 + lane] : 0.f;
#pragma unroll 4
    for (int k = 0; k < 64; ++k) {
        float w = Wl[k * 64 + lane];
#pragma unroll
        for (int i = 0; i < 4; ++i) acc[i] += bcast(hv[i], k) * w;
    }
    float as = a_s[lane], ad = a_d[lane];
#pragma unroll
    for (int i = 0; i < 4; ++i) {
        if (n0 + i >= N) break;
        hs[(n0 + i) * 64 + lane] = acc[i];
        float ps = acc[i] * as;
        float pd = acc[i] * ad;
        for (int m = 32; m; m >>= 1) { ps += __shfl_xor(ps, m, 64); pd += __shfl_xor(pd, m, 64); }
        if (lane == 0) { asrc[n0 + i] = ps; adst[n0 + i] = pd; }
    }
}

__global__ void layer_init_kernel(float* __restrict__ go, const float* __restrict__ bias,
                                  float* __restrict__ den, unsigned* __restrict__ amax,
                                  double* __restrict__ stats, int N) {
    int i = blockIdx.x * blockDim.x + threadIdx.x;
    if (i < N * 64) {
        go[i] = bias[i & 63];
        if ((i & 63) == 0) { den[i >> 6] = 0.f; amax[i >> 6] = 0u; }
    }
    if (i == 0) { stats[0] = 0.0; stats[1] = 0.0; }
}

__global__ void edge_alpha_kernel(const int* __restrict__ ei, const float* __restrict__ ea,
                                  const float* __restrict__ asrc, const float* __restrict__ adst,
                                  const float* __restrict__ weae, float* __restrict__ alpha,
                                  unsigned* __restrict__ amax, int E) {
    int e = blockIdx.x * blockDim.x + threadIdx.x;
    if (e >= E) return;
    int s = ei[e], d = ei[E + e];
    float2 eav = *reinterpret_cast<const float2*>(&ea[e * 2]);
    float a = asrc[s] + adst[d] + eav.x * weae[0] + eav.y * weae[1];
    a = a > 0.f ? a : 0.2f * a;
    alpha[e] = a;
    atomicMax(&amax[d], fkey(a));
}

__global__ void edge_exp_kernel(const int* __restrict__ ei, float* __restrict__ alpha,
                                const unsigned* __restrict__ amax, float* __restrict__ den,
                                int E) {
    int e = blockIdx.x * blockDim.x + threadIdx.x;
    if (e >= E) return;
    int d = ei[E + e];
    float ex = __expf(alpha[e] - fdecode(amax[d]));
    alpha[e] = ex;
    unsafeAtomicAdd(&den[d], ex);
}

__global__ void edge_message_kernel(const int* __restrict__ ei, const float* __restrict__ hs,
                                    const float* __restrict__ alpha, const float* __restrict__ den,
                                    float* __restrict__ go, int E) {
    int wid = (int)((blockIdx.x * (unsigned)blockDim.x + threadIdx.x) >> 6);
    int lane = threadIdx.x & 63;
    if (wid >= E) return;
    int s = ei[wid], d = ei[E + wid];
    float w = alpha[wid] / (den[d] + 1e-16f);
    unsafeAtomicAdd(&go[d * 64 + lane], hs[s * 64 + lane] * w);
}

__global__ void ln_stats_kernel(const float* __restrict__ go, double* __restrict__ stats, int M) {
    double s = 0, ss = 0;
    for (int i = blockIdx.x * blockDim.x + threadIdx.x; i < M; i += gridDim.x * blockDim.x) {
        float v = go[i];
        s += v; ss += (double)v * v;
    }
    for (int m = 32; m; m >>= 1) { s += __shfl_xor(s, m, 64); ss += __shfl_xor(ss, m, 64); }
    __shared__ double sh[8];
    int wave = threadIdx.x >> 6, lane = threadIdx.x & 63;
    if (lane == 0) { sh[wave * 2] = s; sh[wave * 2 + 1] = ss; }
    __syncthreads();
    if (threadIdx.x == 0) {
        double ts = 0, tss = 0;
        for (int w2 = 0; w2 < 4; ++w2) { ts += sh[w2 * 2]; tss += sh[w2 * 2 + 1]; }
        unsafeAtomicAdd(&stats[0], ts);
        unsafeAtomicAdd(&stats[1], tss);
    }
}

// LN(graph) + ReLU -> h, and fc1acc += relu_out @ W_fc1_slice^T (JK fused)
// 4 nodes per wave.
__global__ void ln_apply_kernel(const float* __restrict__ go, const double* __restrict__ stats,
                                const float* __restrict__ g, const float* __restrict__ b,
                                const float* __restrict__ W_fc1, int lofs,
                                float* __restrict__ h, float* __restrict__ fc1acc, int N) {
    __shared__ float Wl[64 * 64];  // [k][o]
    int tid = threadIdx.x;
    for (int i = tid; i < 4096; i += 256) {
        int k = i >> 6, o = i & 63;
        Wl[i] = W_fc1[o * 320 + lofs + k];
    }
    __syncthreads();
    double M = (double)N * 64.0;
    double mu = stats[0] / M;
    float mean = (float)mu;
    float var = (float)(stats[1] / M - mu * mu);
    float inv = 1.f / (sqrtf(fmaxf(var, 0.f)) + 1e-5f);
    int lane = tid & 63, wave = tid >> 6;
    int n0 = (blockIdx.x * 4 + wave) * 4;
    if (n0 >= N) return;
    float gl = g[lane], bl = b[lane];
    float v[4], acc[4] = {};
#pragma unroll
    for (int i = 0; i < 4; ++i) {
        float t = (n0 + i < N) ? go[(n0 + i) * 64 + lane] : 0.f;
        v[i] = fmaxf((t - mean) * inv * gl + bl, 0.f);
    }
#pragma unroll 4
    for (int k = 0; k < 64; ++k) {
        float w = Wl[k * 64 + lane];
#pragma unroll
        for (int i = 0; i < 4; ++i) acc[i] += bcast(v[i], k) * w;
    }
#pragma unroll
    for (int i = 0; i < 4; ++i) {
        if (n0 + i >= N) break;
        h[(n0 + i) * 64 + lane] = v[i];
        fc1acc[(n0 + i) * 64 + lane] += acc[i];
    }
}

__global__ void head_kernel(const float* __restrict__ fc1acc, const float* __restrict__ b1,
                            const float* __restrict__ W2, const float* __restrict__ b2,
                            float* __restrict__ out, int N) {
    int lane = threadIdx.x & 63, wave = threadIdx.x >> 6;
    int n = blockIdx.x * 4 + wave;
    if (n >= N) return;
    float v = fmaxf(fc1acc[n * 64 + lane] + b1[lane], 0.f);
    float r0 = v * W2[lane];
    float r1 = v * W2[64 + lane];
    for (int m = 32; m; m >>= 1) { r0 += __shfl_xor(r0, m, 64); r1 += __shfl_xor(r1, m, 64); }
    if (lane == 0) { out[n * 2 + 0] = r0 + b2[0]; out[n * 2 + 1] = r1 + b2[1]; }
}

extern "C" void kernel_launch(void* const* d_in, const int* in_sizes, int n_in,
                              void* d_out, int out_size, void* d_ws, size_t ws_size,
                              hipStream_t stream) {
    const float* x        = (const float*)d_in[0];
    const int*   ei       = (const int*)d_in[1];
    const float* ea       = (const float*)d_in[2];
    const float* W_ih     = (const float*)d_in[3];
    const float* W_hh     = (const float*)d_in[4];
    const float* b_ih     = (const float*)d_in[5];
    const float* b_hh     = (const float*)d_in[6];
    const float* W_gat    = (const float*)d_in[7];
    const float* att_src  = (const float*)d_in[8];
    const float* att_dst  = (const float*)d_in[9];
    const float* W_edge   = (const float*)d_in[10];
    const float* att_edge = (const float*)d_in[11];
    const float* b_gat    = (const float*)d_in[12];
    const float* ln_g     = (const float*)d_in[13];
    const float* ln_b     = (const float*)d_in[14];
    const float* W_fc1    = (const float*)d_in[15];
    const float* b_fc1    = (const float*)d_in[16];
    const float* W_fc2    = (const float*)d_in[17];
    const float* b_fc2    = (const float*)d_in[18];
    float* out = (float*)d_out;

    int N = in_sizes[0] / (T_STEPS * 2);
    int E = in_sizes[1] / 2;
    size_t N64 = (size_t)N * 64;

    float* ws   = (float*)d_ws;
    float* h    = ws;
    float* hs   = h + N64;
    float* go   = hs + N64;
    float* fc1  = go + N64;
    float* asrc = fc1 + N64;
    float* adst = asrc + N;
    unsigned* amax = (unsigned*)(adst + N);
    float* den  = (float*)(amax + N);
    float* alpha = den + N;
    float* weae  = alpha + E;
    double* stats = (double*)(((uintptr_t)(weae + 2) + 15) & ~(uintptr_t)15);

    lstm_kernel<<<(N + 63) / 64, 512, 0, stream>>>(x, W_ih, W_hh, b_ih, b_hh, h, fc1, N);
    for (int l = 0; l < 5; ++l) {
        gat_scores_kernel<<<(N + 15) / 16, 256, 0, stream>>>(
            h, W_gat + l * 4096, att_src + l * 64, att_dst + l * 64,
            W_edge + l * 128, att_edge + l * 64, hs, asrc, adst, weae, N);
        layer_init_kernel<<<(N * 64 + 255) / 256, 256, 0, stream>>>(go, b_gat + l * 64, den, amax, stats, N);
        edge_alpha_kernel<<<(E + 255) / 256, 256, 0, stream>>>(ei, ea, asrc, adst, weae, alpha, amax, E);
        edge_exp_kernel<<<(E + 255) / 256, 256, 0, stream>>>(ei, alpha, amax, den, E);
        edge_message_kernel<<<(E + 3) / 4, 256, 0, stream>>>(ei, hs, alpha, den, go, E);
        ln_stats_kernel<<<2048, 256, 0, stream>>>(go, stats, N * 64);
        ln_apply_kernel<<<(N + 15) / 16, 256, 0, stream>>>(go, stats, ln_g + l * 64, ln_b + l * 64,
                                                           W_fc1, l * 64, h, fc1, N);
    }
    head_kernel<<<(N + 3) / 4, 256, 0, stream>>>(fc1, b_fc1, W_fc2, b_fc2, out, N);
}

// Round 4
// 3212.978 us; speedup vs baseline: 1.5995x; 1.3333x over previous
//
#include <hip/hip_runtime.h>
#include <hip/hip_bf16.h>
#include <cstdint>

#define T_STEPS 24

typedef __attribute__((ext_vector_type(8))) short bf16x8;
typedef __attribute__((ext_vector_type(16))) float f32x16;

__device__ __forceinline__ float bcast(float v, int lane) {
    return __int_as_float(__builtin_amdgcn_readlane(__float_as_int(v), lane));
}
__device__ __forceinline__ float sigm(float x) {
    return 1.f / (1.f + __expf(-x));
}
__device__ __forceinline__ float tanh_(float x) {
    float t = __expf(2.f * x);
    return 1.f - 2.f / (t + 1.f);
}
__device__ __forceinline__ unsigned fkey(float f) {
    unsigned u = __float_as_uint(f);
    return (u & 0x80000000u) ? ~u : (u | 0x80000000u);
}
__device__ __forceinline__ float fdecode(unsigned k) {
    unsigned u = (k & 0x80000000u) ? (k ^ 0x80000000u) : ~k;
    return __uint_as_float(u);
}
__device__ __forceinline__ ushort bf_rne(float v) {
    unsigned u = __float_as_uint(v);
    u += 0x7FFFu + ((u >> 16) & 1u);
    return (ushort)(u >> 16);
}
__device__ __forceinline__ float bf_dec(ushort h) {
    return __uint_as_float(((unsigned)h) << 16);
}

// ---- Prep: build frag-linear bf16 hi/lo W_hh tables + augment (W_ih|bias)
// Layout in wf (ushort):
//   [0, 16384)      W_hh hi  frags: [(tile*4+chunk)*64 + lane]*8 + j
//   [16384, 32768)  W_hh lo  frags
//   [32768, 36864)  B2 augment frags: [tile*64 + lane]*8 + j
__global__ void lstm_prep_kernel(const float* __restrict__ W_hh,
                                 const float* __restrict__ W_ih,
                                 const float* __restrict__ b_ih,
                                 const float* __restrict__ b_hh,
                                 ushort* __restrict__ wf) {
    int idx = blockIdx.x * 256 + threadIdx.x;
    if (idx < 2048) {  // W_hh frags
        int l = idx & 63, chunk = (idx >> 6) & 3, tile = idx >> 8;
        int gate = tile * 32 + (l & 31);
        int k0 = chunk * 16 + (l >> 5) * 8;
        ushort* hi = wf + idx * 8;
        ushort* lo = wf + 16384 + idx * 8;
        for (int j = 0; j < 8; ++j) {
            float v = W_hh[gate * 64 + k0 + j];
            ushort h = bf_rne(v);
            hi[j] = h;
            lo[j] = bf_rne(v - bf_dec(h));
        }
    } else if (idx < 2048 + 512) {  // augment frags
        int i2 = idx - 2048;
        int l = i2 & 63, tile = i2 >> 6;
        ushort* d = wf + 32768 + i2 * 8;
        ushort v[8] = {0, 0, 0, 0, 0, 0, 0, 0};
        if (l < 32) {
            int gate = tile * 32 + l;
            float w0 = W_ih[gate * 2 + 0], w1 = W_ih[gate * 2 + 1];
            float b = b_ih[gate] + b_hh[gate];
            ushort w0h = bf_rne(w0), w1h = bf_rne(w1);
            v[0] = w0h; v[1] = w1h; v[2] = bf_rne(b);
            v[3] = w0h; v[4] = w1h;
            v[5] = bf_rne(w0 - bf_dec(w0h));
            v[6] = bf_rne(w1 - bf_dec(w1h));
        }
        for (int j = 0; j < 8; ++j) d[j] = v[j];
    }
}

// ---- MFMA LSTM: 512-thr block = 8 waves, 32 nodes/wave via 32x32x16 bf16.
// Split hi/lo bf16 => ~f32-exact. LDS: W frags 72KB shared + 8KB/wave h tile.
__global__ __launch_bounds__(512, 2) void lstm_kernel(
        const float* __restrict__ x, const ushort* __restrict__ wf,
        float* __restrict__ h_out, float* __restrict__ fc1acc, int N) {
    extern __shared__ char smem[];
    int tid = threadIdx.x;
    {   // stage all frag tables (73728 B) linearly
        const uint4* src = (const uint4*)wf;
        uint4* dst = (uint4*)smem;
        for (int i = tid; i < 73728 / 16; i += 512) dst[i] = src[i];
    }
    __syncthreads();
    int l = tid & 63, wave = tid >> 6;
    int n0 = (blockIdx.x * 8 + wave) * 32;
    char* hmem = smem + 73728 + wave * 8192;  // [32 rows][64 ch] f32, XOR-swizzled
    for (int i = l; i < 2048; i += 64) ((float*)hmem)[i] = 0.f;

    float c_regs[32];
#pragma unroll
    for (int i = 0; i < 32; ++i) c_regs[i] = 0.f;

    const int row_a = l & 31;
    const int kg = (l >> 5) * 8;

    for (int t = 0; t < T_STEPS; ++t) {
        // x gather (lanes < 32 own one node each)
        float x0 = 0.f, x1 = 0.f;
        if (l < 32 && (n0 + l) < N) {
            const float* xp = x + ((size_t)(n0 + l) * T_STEPS + t) * 2;
            x0 = xp[0]; x1 = xp[1];
        }
        // A frags (hi/lo) from swizzled h tile
        bf16x8 ahi[4], alo[4];
#pragma unroll
        for (int c = 0; c < 4; ++c) {
            float hv[8];
#pragma unroll
            for (int half = 0; half < 2; ++half) {
                int colb = (c * 16 + kg + half * 4) * 4;
                unsigned addr = (unsigned)(row_a * 256 + colb) ^ ((row_a & 7) << 4);
                float4 v = *(const float4*)(hmem + addr);
                hv[half * 4 + 0] = v.x; hv[half * 4 + 1] = v.y;
                hv[half * 4 + 2] = v.z; hv[half * 4 + 3] = v.w;
            }
#pragma unroll
            for (int j = 0; j < 8; ++j) {
                ushort hb = bf_rne(hv[j]);
                ahi[c][j] = (short)hb;
                alo[c][j] = (short)bf_rne(hv[j] - bf_dec(hb));
            }
        }
        // augment A2 = [x0h,x1h,1,x0l,x1l,x0h,x1h,0] (k=8..15 rows of B2 are 0)
        ushort x0h = bf_rne(x0), x1h = bf_rne(x1);
        bf16x8 a2;
        a2[0] = (short)x0h; a2[1] = (short)x1h; a2[2] = (short)0x3F80;
        a2[3] = (short)bf_rne(x0 - bf_dec(x0h));
        a2[4] = (short)bf_rne(x1 - bf_dec(x1h));
        a2[5] = (short)x0h; a2[6] = (short)x1h; a2[7] = 0;

#pragma unroll
        for (int cb = 0; cb < 2; ++cb) {
            f32x16 acc[4];
#pragma unroll
            for (int g = 0; g < 4; ++g) {
                int tile = g * 2 + cb;
                bf16x8 b2 = *(const bf16x8*)(smem + 65536 + (tile * 64 + l) * 16);
                f32x16 z = {};
                acc[g] = __builtin_amdgcn_mfma_f32_32x32x16_bf16(a2, b2, z, 0, 0, 0);
            }
#pragma unroll
            for (int c = 0; c < 4; ++c) {
#pragma unroll
                for (int g = 0; g < 4; ++g) {
                    int tile = g * 2 + cb;
                    const char* bp = smem + ((tile * 4 + c) * 64 + l) * 16;
                    bf16x8 bhi = *(const bf16x8*)bp;
                    bf16x8 blo = *(const bf16x8*)(bp + 32768);
                    acc[g] = __builtin_amdgcn_mfma_f32_32x32x16_bf16(ahi[c], bhi, acc[g], 0, 0, 0);
                    acc[g] = __builtin_amdgcn_mfma_f32_32x32x16_bf16(alo[c], bhi, acc[g], 0, 0, 0);
                    acc[g] = __builtin_amdgcn_mfma_f32_32x32x16_bf16(ahi[c], blo, acc[g], 0, 0, 0);
                }
            }
#pragma unroll
            for (int r = 0; r < 16; ++r) {
                float iv = acc[0][r], fv = acc[1][r], gv = acc[2][r], ov = acc[3][r];
                float co = c_regs[cb * 16 + r];
                float cn = sigm(fv) * co + sigm(iv) * tanh_(gv);
                float hn = sigm(ov) * tanh_(cn);
                c_regs[cb * 16 + r] = cn;
                int row = (r & 3) + 8 * (r >> 2) + 4 * (l >> 5);
                unsigned addr = (unsigned)(row * 256 + (cb * 32 + (l & 31)) * 4) ^ ((row & 7) << 4);
                *(float*)(hmem + addr) = hn;
            }
        }
    }
    // write h + zero fc1acc (lane l -> node row l>>1, ch half (l&1)*32)
    int row = l >> 1, chb = (l & 1) * 32;
    int node = n0 + row;
    if (node < N) {
#pragma unroll
        for (int q = 0; q < 8; ++q) {
            int colb = (chb + q * 4) * 4;
            unsigned addr = (unsigned)(row * 256 + colb) ^ ((row & 7) << 4);
            float4 v = *(const float4*)(hmem + addr);
            *(float4*)(h_out + (size_t)node * 64 + chb + q * 4) = v;
            float4 zz = {0.f, 0.f, 0.f, 0.f};
            *(float4*)(fc1acc + (size_t)node * 64 + chb + q * 4) = zz;
        }
    }
}

// ---------------- GAT per-node: hs = h@W, asrc/adst scores, we_ae ----------
__global__ void gat_scores_kernel(const float* __restrict__ h,
                                  const float* __restrict__ Wg,
                                  const float* __restrict__ a_s,
                                  const float* __restrict__ a_d,
                                  const float* __restrict__ W_e,
                                  const float* __restrict__ a_e,
                                  float* __restrict__ hs,
                                  float* __restrict__ asrc,
                                  float* __restrict__ adst,
                                  float* __restrict__ weae,
                                  int N) {
    __shared__ float Wl[64 * 64];  // [k][j]
    int tid = threadIdx.x;
    for (int i = tid; i < 4096; i += 256) Wl[i] = Wg[i];
    __syncthreads();
    if (blockIdx.x == 0 && tid < 2) {
        float s = 0;
        for (int j = 0; j < 64; ++j) s += W_e[tid * 64 + j] * a_e[j];
        weae[tid] = s;
    }
    int lane = tid & 63, wave = tid >> 6;
    int n0 = (blockIdx.x * 4 + wave) * 4;
    if (n0 >= N) return;
    float hv[4], acc[4] = {};
#pragma unroll
    for (int i = 0; i < 4; ++i) hv[i] = (n0 + i < N) ? h[(n0 + i) * 64 + lane] : 0.f;
#pragma unroll 4
    for (int k = 0; k < 64; ++k) {
        float w = Wl[k * 64 + lane];
#pragma unroll
        for (int i = 0; i < 4; ++i) acc[i] += bcast(hv[i], k) * w;
    }
    float as = a_s[lane], ad = a_d[lane];
#pragma unroll
    for (int i = 0; i < 4; ++i) {
        if (n0 + i >= N) break;
        hs[(n0 + i) * 64 + lane] = acc[i];
        float ps = acc[i] * as;
        float pd = acc[i] * ad;
        for (int m = 32; m; m >>= 1) { ps += __shfl_xor(ps, m, 64); pd += __shfl_xor(pd, m, 64); }
        if (lane == 0) { asrc[n0 + i] = ps; adst[n0 + i] = pd; }
    }
}

__global__ void layer_init_kernel(float* __restrict__ go, const float* __restrict__ bias,
                                  float* __restrict__ den, unsigned* __restrict__ amax,
                                  double* __restrict__ stats, int N) {
    int i = blockIdx.x * blockDim.x + threadIdx.x;
    if (i < N * 64) {
        go[i] = bias[i & 63];
        if ((i & 63) == 0) { den[i >> 6] = 0.f; amax[i >> 6] = 0u; }
    }
    if (i == 0) { stats[0] = 0.0; stats[1] = 0.0; }
}

__global__ void edge_alpha_kernel(const int* __restrict__ ei, const float* __restrict__ ea,
                                  const float* __restrict__ asrc, const float* __restrict__ adst,
                                  const float* __restrict__ weae, float* __restrict__ alpha,
                                  unsigned* __restrict__ amax, int E) {
    int e = blockIdx.x * blockDim.x + threadIdx.x;
    if (e >= E) return;
    int s = ei[e], d = ei[E + e];
    float2 eav = *reinterpret_cast<const float2*>(&ea[e * 2]);
    float a = asrc[s] + adst[d] + eav.x * weae[0] + eav.y * weae[1];
    a = a > 0.f ? a : 0.2f * a;
    alpha[e] = a;
    atomicMax(&amax[d], fkey(a));
}

__global__ void edge_exp_kernel(const int* __restrict__ ei, float* __restrict__ alpha,
                                const unsigned* __restrict__ amax, float* __restrict__ den,
                                int E) {
    int e = blockIdx.x * blockDim.x + threadIdx.x;
    if (e >= E) return;
    int d = ei[E + e];
    float ex = __expf(alpha[e] - fdecode(amax[d]));
    alpha[e] = ex;
    unsafeAtomicAdd(&den[d], ex);
}

__global__ void edge_message_kernel(const int* __restrict__ ei, const float* __restrict__ hs,
                                    const float* __restrict__ alpha, const float* __restrict__ den,
                                    float* __restrict__ go, int E) {
    int wid = (int)((blockIdx.x * (unsigned)blockDim.x + threadIdx.x) >> 6);
    int lane = threadIdx.x & 63;
    if (wid >= E) return;
    int s = ei[wid], d = ei[E + wid];
    float w = alpha[wid] / (den[d] + 1e-16f);
    unsafeAtomicAdd(&go[d * 64 + lane], hs[s * 64 + lane] * w);
}

__global__ void ln_stats_kernel(const float* __restrict__ go, double* __restrict__ stats, int M) {
    double s = 0, ss = 0;
    for (int i = blockIdx.x * blockDim.x + threadIdx.x; i < M; i += gridDim.x * blockDim.x) {
        float v = go[i];
        s += v; ss += (double)v * v;
    }
    for (int m = 32; m; m >>= 1) { s += __shfl_xor(s, m, 64); ss += __shfl_xor(ss, m, 64); }
    __shared__ double sh[8];
    int wave = threadIdx.x >> 6, lane = threadIdx.x & 63;
    if (lane == 0) { sh[wave * 2] = s; sh[wave * 2 + 1] = ss; }
    __syncthreads();
    if (threadIdx.x == 0) {
        double ts = 0, tss = 0;
        for (int w2 = 0; w2 < 4; ++w2) { ts += sh[w2 * 2]; tss += sh[w2 * 2 + 1]; }
        unsafeAtomicAdd(&stats[0], ts);
        unsafeAtomicAdd(&stats[1], tss);
    }
}

// LN(graph) + ReLU -> h, and fc1acc += relu_out @ W_fc1_slice^T (JK fused)
__global__ void ln_apply_kernel(const float* __restrict__ go, const double* __restrict__ stats,
                                const float* __restrict__ g, const float* __restrict__ b,
                                const float* __restrict__ W_fc1, int lofs,
                                float* __restrict__ h, float* __restrict__ fc1acc, int N) {
    __shared__ float Wl[64 * 64];  // [k][o]
    int tid = threadIdx.x;
    for (int i = tid; i < 4096; i += 256) {
        int k = i >> 6, o = i & 63;
        Wl[i] = W_fc1[o * 320 + lofs + k];
    }
    __syncthreads();
    double M = (double)N * 64.0;
    double mu = stats[0] / M;
    float mean = (float)mu;
    float var = (float)(stats[1] / M - mu * mu);
    float inv = 1.f / (sqrtf(fmaxf(var, 0.f)) + 1e-5f);
    int lane = tid & 63, wave = tid >> 6;
    int n0 = (blockIdx.x * 4 + wave) * 4;
    if (n0 >= N) return;
    float gl = g[lane], bl = b[lane];
    float v[4], acc[4] = {};
#pragma unroll
    for (int i = 0; i < 4; ++i) {
        float t = (n0 + i < N) ? go[(n0 + i) * 64 + lane] : 0.f;
        v[i] = fmaxf((t - mean) * inv * gl + bl, 0.f);
    }
#pragma unroll 4
    for (int k = 0; k < 64; ++k) {
        float w = Wl[k * 64 + lane];
#pragma unroll
        for (int i = 0; i < 4; ++i) acc[i] += bcast(v[i], k) * w;
    }
#pragma unroll
    for (int i = 0; i < 4; ++i) {
        if (n0 + i >= N) break;
        h[(n0 + i) * 64 + lane] = v[i];
        fc1acc[(n0 + i) * 64 + lane] += acc[i];
    }
}

__global__ void head_kernel(const float* __restrict__ fc1acc, const float* __restrict__ b1,
                            const float* __restrict__ W2, const float* __restrict__ b2,
                            float* __restrict__ out, int N) {
    int lane = threadIdx.x & 63, wave = threadIdx.x >> 6;
    int n = blockIdx.x * 4 + wave;
    if (n >= N) return;
    float v = fmaxf(fc1acc[n * 64 + lane] + b1[lane], 0.f);
    float r0 = v * W2[lane];
    float r1 = v * W2[64 + lane];
    for (int m = 32; m; m >>= 1) { r0 += __shfl_xor(r0, m, 64); r1 += __shfl_xor(r1, m, 64); }
    if (lane == 0) { out[n * 2 + 0] = r0 + b2[0]; out[n * 2 + 1] = r1 + b2[1]; }
}

extern "C" void kernel_launch(void* const* d_in, const int* in_sizes, int n_in,
                              void* d_out, int out_size, void* d_ws, size_t ws_size,
                              hipStream_t stream) {
    const float* x        = (const float*)d_in[0];
    const int*   ei       = (const int*)d_in[1];
    const float* ea       = (const float*)d_in[2];
    const float* W_ih     = (const float*)d_in[3];
    const float* W_hh     = (const float*)d_in[4];
    const float* b_ih     = (const float*)d_in[5];
    const float* b_hh     = (const float*)d_in[6];
    const float* W_gat    = (const float*)d_in[7];
    const float* att_src  = (const float*)d_in[8];
    const float* att_dst  = (const float*)d_in[9];
    const float* W_edge   = (const float*)d_in[10];
    const float* att_edge = (const float*)d_in[11];
    const float* b_gat    = (const float*)d_in[12];
    const float* ln_g     = (const float*)d_in[13];
    const float* ln_b     = (const float*)d_in[14];
    const float* W_fc1    = (const float*)d_in[15];
    const float* b_fc1    = (const float*)d_in[16];
    const float* W_fc2    = (const float*)d_in[17];
    const float* b_fc2    = (const float*)d_in[18];
    float* out = (float*)d_out;

    int N = in_sizes[0] / (T_STEPS * 2);
    int E = in_sizes[1] / 2;
    size_t N64 = (size_t)N * 64;

    float* ws   = (float*)d_ws;
    float* h    = ws;
    float* hs   = h + N64;
    float* go   = hs + N64;
    float* fc1  = go + N64;
    float* asrc = fc1 + N64;
    float* adst = asrc + N;
    unsigned* amax = (unsigned*)(adst + N);
    float* den  = (float*)(amax + N);
    float* alpha = den + N;
    float* weae  = alpha + E;
    double* stats = (double*)(((uintptr_t)(weae + 2) + 15) & ~(uintptr_t)15);
    ushort* wfrag = (ushort*)(stats + 2);

    lstm_prep_kernel<<<10, 256, 0, stream>>>(W_hh, W_ih, b_ih, b_hh, wfrag);
    lstm_kernel<<<(N + 255) / 256, 512, 139264, stream>>>(x, wfrag, h, fc1, N);
    for (int l = 0; l < 5; ++l) {
        gat_scores_kernel<<<(N + 15) / 16, 256, 0, stream>>>(
            h, W_gat + l * 4096, att_src + l * 64, att_dst + l * 64,
            W_edge + l * 128, att_edge + l * 64, hs, asrc, adst, weae, N);
        layer_init_kernel<<<(N * 64 + 255) / 256, 256, 0, stream>>>(go, b_gat + l * 64, den, amax, stats, N);
        edge_alpha_kernel<<<(E + 255) / 256, 256, 0, stream>>>(ei, ea, asrc, adst, weae, alpha, amax, E);
        edge_exp_kernel<<<(E + 255) / 256, 256, 0, stream>>>(ei, alpha, amax, den, E);
        edge_message_kernel<<<(E + 3) / 4, 256, 0, stream>>>(ei, hs, alpha, den, go, E);
        ln_stats_kernel<<<2048, 256, 0, stream>>>(go, stats, N * 64);
        ln_apply_kernel<<<(N + 15) / 16, 256, 0, stream>>>(go, stats, ln_g + l * 64, ln_b + l * 64,
                                                           W_fc1, l * 64, h, fc1, N);
    }
    head_kernel<<<(N + 3) / 4, 256, 0, stream>>>(fc1, b_fc1, W_fc2, b_fc2, out, N);
}

// Round 5
// 1981.404 us; speedup vs baseline: 2.5938x; 1.6216x over previous
//
#include <hip/hip_runtime.h>
#include <hip/hip_bf16.h>
#include <cstdint>

#define T_STEPS 24

typedef __attribute__((ext_vector_type(8))) short bf16x8;
typedef __attribute__((ext_vector_type(16))) float f32x16;

__device__ __forceinline__ float bcast(float v, int lane) {
    return __int_as_float(__builtin_amdgcn_readlane(__float_as_int(v), lane));
}
__device__ __forceinline__ float sigm(float x) {
    return 1.f / (1.f + __expf(-x));
}
__device__ __forceinline__ float tanh_(float x) {
    float t = __expf(2.f * x);
    return 1.f - 2.f / (t + 1.f);
}
__device__ __forceinline__ ushort bf_rne(float v) {
    unsigned u = __float_as_uint(v);
    u += 0x7FFFu + ((u >> 16) & 1u);
    return (ushort)(u >> 16);
}
__device__ __forceinline__ float bf_dec(ushort h) {
    return __uint_as_float(((unsigned)h) << 16);
}

// ---- Prep: build frag-linear bf16 hi/lo W_hh tables + augment (W_ih|bias)
__global__ void lstm_prep_kernel(const float* __restrict__ W_hh,
                                 const float* __restrict__ W_ih,
                                 const float* __restrict__ b_ih,
                                 const float* __restrict__ b_hh,
                                 ushort* __restrict__ wf) {
    int idx = blockIdx.x * 256 + threadIdx.x;
    if (idx < 2048) {  // W_hh frags
        int l = idx & 63, chunk = (idx >> 6) & 3, tile = idx >> 8;
        int gate = tile * 32 + (l & 31);
        int k0 = chunk * 16 + (l >> 5) * 8;
        ushort* hi = wf + idx * 8;
        ushort* lo = wf + 16384 + idx * 8;
        for (int j = 0; j < 8; ++j) {
            float v = W_hh[gate * 64 + k0 + j];
            ushort h = bf_rne(v);
            hi[j] = h;
            lo[j] = bf_rne(v - bf_dec(h));
        }
    } else if (idx < 2048 + 512) {  // augment frags
        int i2 = idx - 2048;
        int l = i2 & 63, tile = i2 >> 6;
        ushort* d = wf + 32768 + i2 * 8;
        ushort v[8] = {0, 0, 0, 0, 0, 0, 0, 0};
        if (l < 32) {
            int gate = tile * 32 + l;
            float w0 = W_ih[gate * 2 + 0], w1 = W_ih[gate * 2 + 1];
            float b = b_ih[gate] + b_hh[gate];
            ushort w0h = bf_rne(w0), w1h = bf_rne(w1);
            v[0] = w0h; v[1] = w1h; v[2] = bf_rne(b);
            v[3] = w0h; v[4] = w1h;
            v[5] = bf_rne(w0 - bf_dec(w0h));
            v[6] = bf_rne(w1 - bf_dec(w1h));
        }
        for (int j = 0; j < 8; ++j) d[j] = v[j];
    }
}

// ---- MFMA LSTM: 512-thr block = 8 waves, 32 nodes/wave via 32x32x16 bf16.
__global__ __launch_bounds__(512, 2) void lstm_kernel(
        const float* __restrict__ x, const ushort* __restrict__ wf,
        float* __restrict__ h_out, float* __restrict__ fc1acc, int N) {
    extern __shared__ char smem[];
    int tid = threadIdx.x;
    {
        const uint4* src = (const uint4*)wf;
        uint4* dst = (uint4*)smem;
        for (int i = tid; i < 73728 / 16; i += 512) dst[i] = src[i];
    }
    __syncthreads();
    int l = tid & 63, wave = tid >> 6;
    int n0 = (blockIdx.x * 8 + wave) * 32;
    char* hmem = smem + 73728 + wave * 8192;
    for (int i = l; i < 2048; i += 64) ((float*)hmem)[i] = 0.f;

    float c_regs[32];
#pragma unroll
    for (int i = 0; i < 32; ++i) c_regs[i] = 0.f;

    const int row_a = l & 31;
    const int kg = (l >> 5) * 8;

    for (int t = 0; t < T_STEPS; ++t) {
        float x0 = 0.f, x1 = 0.f;
        if (l < 32 && (n0 + l) < N) {
            const float* xp = x + ((size_t)(n0 + l) * T_STEPS + t) * 2;
            x0 = xp[0]; x1 = xp[1];
        }
        bf16x8 ahi[4], alo[4];
#pragma unroll
        for (int c = 0; c < 4; ++c) {
            float hv[8];
#pragma unroll
            for (int half = 0; half < 2; ++half) {
                int colb = (c * 16 + kg + half * 4) * 4;
                unsigned addr = (unsigned)(row_a * 256 + colb) ^ ((row_a & 7) << 4);
                float4 v = *(const float4*)(hmem + addr);
                hv[half * 4 + 0] = v.x; hv[half * 4 + 1] = v.y;
                hv[half * 4 + 2] = v.z; hv[half * 4 + 3] = v.w;
            }
#pragma unroll
            for (int j = 0; j < 8; ++j) {
                ushort hb = bf_rne(hv[j]);
                ahi[c][j] = (short)hb;
                alo[c][j] = (short)bf_rne(hv[j] - bf_dec(hb));
            }
        }
        ushort x0h = bf_rne(x0), x1h = bf_rne(x1);
        bf16x8 a2;
        a2[0] = (short)x0h; a2[1] = (short)x1h; a2[2] = (short)0x3F80;
        a2[3] = (short)bf_rne(x0 - bf_dec(x0h));
        a2[4] = (short)bf_rne(x1 - bf_dec(x1h));
        a2[5] = (short)x0h; a2[6] = (short)x1h; a2[7] = 0;

#pragma unroll
        for (int cb = 0; cb < 2; ++cb) {
            f32x16 acc[4];
#pragma unroll
            for (int g = 0; g < 4; ++g) {
                int tile = g * 2 + cb;
                bf16x8 b2 = *(const bf16x8*)(smem + 65536 + (tile * 64 + l) * 16);
                f32x16 z = {};
                acc[g] = __builtin_amdgcn_mfma_f32_32x32x16_bf16(a2, b2, z, 0, 0, 0);
            }
#pragma unroll
            for (int c = 0; c < 4; ++c) {
#pragma unroll
                for (int g = 0; g < 4; ++g) {
                    int tile = g * 2 + cb;
                    const char* bp = smem + ((tile * 4 + c) * 64 + l) * 16;
                    bf16x8 bhi = *(const bf16x8*)bp;
                    bf16x8 blo = *(const bf16x8*)(bp + 32768);
                    acc[g] = __builtin_amdgcn_mfma_f32_32x32x16_bf16(ahi[c], bhi, acc[g], 0, 0, 0);
                    acc[g] = __builtin_amdgcn_mfma_f32_32x32x16_bf16(alo[c], bhi, acc[g], 0, 0, 0);
                    acc[g] = __builtin_amdgcn_mfma_f32_32x32x16_bf16(ahi[c], blo, acc[g], 0, 0, 0);
                }
            }
#pragma unroll
            for (int r = 0; r < 16; ++r) {
                float iv = acc[0][r], fv = acc[1][r], gv = acc[2][r], ov = acc[3][r];
                float co = c_regs[cb * 16 + r];
                float cn = sigm(fv) * co + sigm(iv) * tanh_(gv);
                float hn = sigm(ov) * tanh_(cn);
                c_regs[cb * 16 + r] = cn;
                int row = (r & 3) + 8 * (r >> 2) + 4 * (l >> 5);
                unsigned addr = (unsigned)(row * 256 + (cb * 32 + (l & 31)) * 4) ^ ((row & 7) << 4);
                *(float*)(hmem + addr) = hn;
            }
        }
    }
    int row = l >> 1, chb = (l & 1) * 32;
    int node = n0 + row;
    if (node < N) {
#pragma unroll
        for (int q = 0; q < 8; ++q) {
            int colb = (chb + q * 4) * 4;
            unsigned addr = (unsigned)(row * 256 + colb) ^ ((row & 7) << 4);
            float4 v = *(const float4*)(hmem + addr);
            *(float4*)(h_out + (size_t)node * 64 + chb + q * 4) = v;
            float4 zz = {0.f, 0.f, 0.f, 0.f};
            *(float4*)(fc1acc + (size_t)node * 64 + chb + q * 4) = zz;
        }
    }
}

// ---------------- CSR build (dst-bucketed), once per call ----------------
__global__ void csr_zero_kernel(int* __restrict__ deg, int N) {
    int i = blockIdx.x * 256 + threadIdx.x;
    if (i < N) deg[i] = 0;
}
__global__ void csr_hist_kernel(const int* __restrict__ ei, int* __restrict__ deg, int E) {
    int e = blockIdx.x * 256 + threadIdx.x;
    if (e < E) atomicAdd(&deg[ei[E + e]], 1);
}
__global__ void csr_scan1_kernel(const int* __restrict__ deg, int* __restrict__ rowptr,
                                 int* __restrict__ bsum, int N) {
    __shared__ int sh[256];
    int tid = threadIdx.x;
    int base = blockIdx.x * 1024 + tid * 4;
    int d0 = base + 0 < N ? deg[base + 0] : 0;
    int d1 = base + 1 < N ? deg[base + 1] : 0;
    int d2 = base + 2 < N ? deg[base + 2] : 0;
    int d3 = base + 3 < N ? deg[base + 3] : 0;
    int tsum = d0 + d1 + d2 + d3;
    sh[tid] = tsum;
    __syncthreads();
    for (int off = 1; off < 256; off <<= 1) {
        int v = 0;
        if (tid >= off) v = sh[tid - off];
        __syncthreads();
        if (tid >= off) sh[tid] += v;
        __syncthreads();
    }
    int excl = sh[tid] - tsum;
    if (base + 0 < N) rowptr[base + 0] = excl;
    if (base + 1 < N) rowptr[base + 1] = excl + d0;
    if (base + 2 < N) rowptr[base + 2] = excl + d0 + d1;
    if (base + 3 < N) rowptr[base + 3] = excl + d0 + d1 + d2;
    if (tid == 255) bsum[blockIdx.x] = sh[255];
}
__global__ void csr_scan2_kernel(int* __restrict__ bsum, int* __restrict__ rowptr,
                                 int nb, int N) {
    if (threadIdx.x == 0 && blockIdx.x == 0) {
        int running = 0;
        for (int b = 0; b < nb; ++b) {
            int t = bsum[b];
            bsum[b] = running;
            running += t;
        }
        rowptr[N] = running;
    }
}
__global__ void csr_scan3_kernel(int* __restrict__ rowptr, int* __restrict__ cursor,
                                 const int* __restrict__ bsum, int N) {
    int tid = threadIdx.x;
    int base = blockIdx.x * 1024 + tid * 4;
    int ofs = bsum[blockIdx.x];
#pragma unroll
    for (int j = 0; j < 4; ++j) {
        if (base + j < N) {
            int v = rowptr[base + j] + ofs;
            rowptr[base + j] = v;
            cursor[base + j] = v;
        }
    }
}
__global__ void csr_scatter_kernel(const int* __restrict__ ei, int* __restrict__ cursor,
                                   int* __restrict__ csr_src, int* __restrict__ csr_eid,
                                   int E) {
    int e = blockIdx.x * 256 + threadIdx.x;
    if (e >= E) return;
    int s = ei[e], d = ei[E + e];
    int pos = atomicAdd(&cursor[d], 1);
    csr_src[pos] = s;
    csr_eid[pos] = e;
}

// ---------------- GAT per-node: hs = h@W, asrc/adst scores, we_ae ----------
__global__ void gat_scores_kernel(const float* __restrict__ h,
                                  const float* __restrict__ Wg,
                                  const float* __restrict__ a_s,
                                  const float* __restrict__ a_d,
                                  const float* __restrict__ W_e,
                                  const float* __restrict__ a_e,
                                  float* __restrict__ hs,
                                  float* __restrict__ asrc,
                                  float* __restrict__ adst,
                                  float* __restrict__ weae,
                                  double* __restrict__ stats,
                                  int N) {
    __shared__ float Wl[64 * 64];  // [k][j]
    int tid = threadIdx.x;
    for (int i = tid; i < 4096; i += 256) Wl[i] = Wg[i];
    __syncthreads();
    if (blockIdx.x == 0) {
        if (tid < 2) {
            float s = 0;
            for (int j = 0; j < 64; ++j) s += W_e[tid * 64 + j] * a_e[j];
            weae[tid] = s;
        } else if (tid < 4) {
            stats[tid - 2] = 0.0;
        }
    }
    int lane = tid & 63, wave = tid >> 6;
    int n0 = (blockIdx.x * 4 + wave) * 4;
    if (n0 >= N) return;
    float hv[4], acc[4] = {};
#pragma unroll
    for (int i = 0; i < 4; ++i) hv[i] = (n0 + i < N) ? h[(n0 + i) * 64 + lane] : 0.f;
#pragma unroll 4
    for (int k = 0; k < 64; ++k) {
        float w = Wl[k * 64 + lane];
#pragma unroll
        for (int i = 0; i < 4; ++i) acc[i] += bcast(hv[i], k) * w;
    }
    float as = a_s[lane], ad = a_d[lane];
#pragma unroll
    for (int i = 0; i < 4; ++i) {
        if (n0 + i >= N) break;
        hs[(n0 + i) * 64 + lane] = acc[i];
        float ps = acc[i] * as;
        float pd = acc[i] * ad;
        for (int m = 32; m; m >>= 1) { ps += __shfl_xor(ps, m, 64); pd += __shfl_xor(pd, m, 64); }
        if (lane == 0) { asrc[n0 + i] = ps; adst[n0 + i] = pd; }
    }
}

// ---- Fused per-dst edge kernel: softmax over in-edges + weighted gather.
// One wave per dst node; lanes own edges (deg<=64 fast path; chunked general).
__global__ void gat_edge_kernel(const int* __restrict__ rowptr,
                                const int* __restrict__ csr_src,
                                const int* __restrict__ csr_eid,
                                const float* __restrict__ ea,
                                const float* __restrict__ asrc,
                                const float* __restrict__ adst,
                                const float* __restrict__ weae,
                                const float* __restrict__ hs,
                                const float* __restrict__ bias,
                                float* __restrict__ go, int N) {
    int lane = threadIdx.x & 63, wave = threadIdx.x >> 6;
    int d = blockIdx.x * 4 + wave;
    if (d >= N) return;
    int start = rowptr[d], deg = rowptr[d + 1] - start;
    float acc = bias[lane];
    if (deg > 0 && deg <= 64) {
        int s = 0;
        float a = -1e30f;
        if (lane < deg) {
            s = csr_src[start + lane];
            int e = csr_eid[start + lane];
            float2 eav = *(const float2*)(ea + (size_t)e * 2);
            a = asrc[s] + adst[d] + eav.x * weae[0] + eav.y * weae[1];
            a = a > 0.f ? a : 0.2f * a;
        }
        float m = a;
        for (int mm = 32; mm; mm >>= 1) m = fmaxf(m, __shfl_xor(m, mm, 64));
        float ex = lane < deg ? __expf(a - m) : 0.f;
        float den = ex;
        for (int mm = 32; mm; mm >>= 1) den += __shfl_xor(den, mm, 64);
        float w = ex / (den + 1e-16f);
        for (int j = 0; j < deg; ++j) {
            int sj = __builtin_amdgcn_readlane(s, j);
            float wj = bcast(w, j);
            acc += wj * hs[(size_t)sj * 64 + lane];
        }
    } else if (deg > 64) {
        float w0 = weae[0], w1 = weae[1], ad = adst[d];
        float m = -1e30f;
        for (int c0 = 0; c0 < deg; c0 += 64) {
            float a = -1e30f;
            if (c0 + lane < deg) {
                int s2 = csr_src[start + c0 + lane];
                int e = csr_eid[start + c0 + lane];
                float2 eav = *(const float2*)(ea + (size_t)e * 2);
                a = asrc[s2] + ad + eav.x * w0 + eav.y * w1;
                a = a > 0.f ? a : 0.2f * a;
            }
            for (int mm = 32; mm; mm >>= 1) a = fmaxf(a, __shfl_xor(a, mm, 64));
            m = fmaxf(m, a);
        }
        float den = 0.f;
        for (int c0 = 0; c0 < deg; c0 += 64) {
            float a = -1e30f;
            if (c0 + lane < deg) {
                int s2 = csr_src[start + c0 + lane];
                int e = csr_eid[start + c0 + lane];
                float2 eav = *(const float2*)(ea + (size_t)e * 2);
                a = asrc[s2] + ad + eav.x * w0 + eav.y * w1;
                a = a > 0.f ? a : 0.2f * a;
            }
            float ex = (c0 + lane < deg) ? __expf(a - m) : 0.f;
            for (int mm = 32; mm; mm >>= 1) ex += __shfl_xor(ex, mm, 64);
            den += ex;
        }
        for (int c0 = 0; c0 < deg; c0 += 64) {
            int s2 = 0;
            float a = -1e30f;
            if (c0 + lane < deg) {
                s2 = csr_src[start + c0 + lane];
                int e = csr_eid[start + c0 + lane];
                float2 eav = *(const float2*)(ea + (size_t)e * 2);
                a = asrc[s2] + ad + eav.x * w0 + eav.y * w1;
                a = a > 0.f ? a : 0.2f * a;
            }
            float w = ((c0 + lane < deg) ? __expf(a - m) : 0.f) / (den + 1e-16f);
            int cnt = deg - c0 < 64 ? deg - c0 : 64;
            for (int j = 0; j < cnt; ++j) {
                int sj = __builtin_amdgcn_readlane(s2, j);
                float wj = bcast(w, j);
                acc += wj * hs[(size_t)sj * 64 + lane];
            }
        }
    }
    go[(size_t)d * 64 + lane] = acc;
}

__global__ void ln_stats_kernel(const float* __restrict__ go, double* __restrict__ stats, int M) {
    double s = 0, ss = 0;
    for (int i = blockIdx.x * blockDim.x + threadIdx.x; i < M; i += gridDim.x * blockDim.x) {
        float v = go[i];
        s += v; ss += (double)v * v;
    }
    for (int m = 32; m; m >>= 1) { s += __shfl_xor(s, m, 64); ss += __shfl_xor(ss, m, 64); }
    __shared__ double sh[8];
    int wave = threadIdx.x >> 6, lane = threadIdx.x & 63;
    if (lane == 0) { sh[wave * 2] = s; sh[wave * 2 + 1] = ss; }
    __syncthreads();
    if (threadIdx.x == 0) {
        double ts = 0, tss = 0;
        for (int w2 = 0; w2 < 4; ++w2) { ts += sh[w2 * 2]; tss += sh[w2 * 2 + 1]; }
        unsafeAtomicAdd(&stats[0], ts);
        unsafeAtomicAdd(&stats[1], tss);
    }
}

// LN(graph) + ReLU -> h, and fc1acc += relu_out @ W_fc1_slice^T (JK fused)
__global__ void ln_apply_kernel(const float* __restrict__ go, const double* __restrict__ stats,
                                const float* __restrict__ g, const float* __restrict__ b,
                                const float* __restrict__ W_fc1, int lofs,
                                float* __restrict__ h, float* __restrict__ fc1acc, int N) {
    __shared__ float Wl[64 * 64];  // [k][o]
    int tid = threadIdx.x;
    for (int i = tid; i < 4096; i += 256) {
        int k = i >> 6, o = i & 63;
        Wl[i] = W_fc1[o * 320 + lofs + k];
    }
    __syncthreads();
    double M = (double)N * 64.0;
    double mu = stats[0] / M;
    float mean = (float)mu;
    float var = (float)(stats[1] / M - mu * mu);
    float inv = 1.f / (sqrtf(fmaxf(var, 0.f)) + 1e-5f);
    int lane = tid & 63, wave = tid >> 6;
    int n0 = (blockIdx.x * 4 + wave) * 4;
    if (n0 >= N) return;
    float gl = g[lane], bl = b[lane];
    float v[4], acc[4] = {};
#pragma unroll
    for (int i = 0; i < 4; ++i) {
        float t = (n0 + i < N) ? go[(n0 + i) * 64 + lane] : 0.f;
        v[i] = fmaxf((t - mean) * inv * gl + bl, 0.f);
    }
#pragma unroll 4
    for (int k = 0; k < 64; ++k) {
        float w = Wl[k * 64 + lane];
#pragma unroll
        for (int i = 0; i < 4; ++i) acc[i] += bcast(v[i], k) * w;
    }
#pragma unroll
    for (int i = 0; i < 4; ++i) {
        if (n0 + i >= N) break;
        h[(n0 + i) * 64 + lane] = v[i];
        fc1acc[(n0 + i) * 64 + lane] += acc[i];
    }
}

__global__ void head_kernel(const float* __restrict__ fc1acc, const float* __restrict__ b1,
                            const float* __restrict__ W2, const float* __restrict__ b2,
                            float* __restrict__ out, int N) {
    int lane = threadIdx.x & 63, wave = threadIdx.x >> 6;
    int n = blockIdx.x * 4 + wave;
    if (n >= N) return;
    float v = fmaxf(fc1acc[n * 64 + lane] + b1[lane], 0.f);
    float r0 = v * W2[lane];
    float r1 = v * W2[64 + lane];
    for (int m = 32; m; m >>= 1) { r0 += __shfl_xor(r0, m, 64); r1 += __shfl_xor(r1, m, 64); }
    if (lane == 0) { out[n * 2 + 0] = r0 + b2[0]; out[n * 2 + 1] = r1 + b2[1]; }
}

extern "C" void kernel_launch(void* const* d_in, const int* in_sizes, int n_in,
                              void* d_out, int out_size, void* d_ws, size_t ws_size,
                              hipStream_t stream) {
    const float* x        = (const float*)d_in[0];
    const int*   ei       = (const int*)d_in[1];
    const float* ea       = (const float*)d_in[2];
    const float* W_ih     = (const float*)d_in[3];
    const float* W_hh     = (const float*)d_in[4];
    const float* b_ih     = (const float*)d_in[5];
    const float* b_hh     = (const float*)d_in[6];
    const float* W_gat    = (const float*)d_in[7];
    const float* att_src  = (const float*)d_in[8];
    const float* att_dst  = (const float*)d_in[9];
    const float* W_edge   = (const float*)d_in[10];
    const float* att_edge = (const float*)d_in[11];
    const float* b_gat    = (const float*)d_in[12];
    const float* ln_g     = (const float*)d_in[13];
    const float* ln_b     = (const float*)d_in[14];
    const float* W_fc1    = (const float*)d_in[15];
    const float* b_fc1    = (const float*)d_in[16];
    const float* W_fc2    = (const float*)d_in[17];
    const float* b_fc2    = (const float*)d_in[18];
    float* out = (float*)d_out;

    int N = in_sizes[0] / (T_STEPS * 2);
    int E = in_sizes[1] / 2;
    size_t N64 = (size_t)N * 64;

    float* ws   = (float*)d_ws;
    float* h    = ws;
    float* hs   = h + N64;
    float* go   = hs + N64;
    float* fc1  = go + N64;
    float* asrc = fc1 + N64;
    float* adst = asrc + N;
    float* weae = adst + N;
    double* stats = (double*)(((uintptr_t)(weae + 2) + 15) & ~(uintptr_t)15);
    ushort* wfrag = (ushort*)(stats + 2);          // 36864 ushorts
    int* deg     = (int*)(wfrag + 36864);
    int* rowptr  = deg + N;                         // N+1
    int* cursor  = rowptr + N + 1;
    int* bsum    = cursor + N;                      // <=128
    int* csr_src = bsum + 128;                      // E
    int* csr_eid = csr_src + E;                     // E

    int nb = (N + 1023) / 1024;

    lstm_prep_kernel<<<10, 256, 0, stream>>>(W_hh, W_ih, b_ih, b_hh, wfrag);
    lstm_kernel<<<(N + 255) / 256, 512, 139264, stream>>>(x, wfrag, h, fc1, N);

    csr_zero_kernel<<<(N + 255) / 256, 256, 0, stream>>>(deg, N);
    csr_hist_kernel<<<(E + 255) / 256, 256, 0, stream>>>(ei, deg, E);
    csr_scan1_kernel<<<nb, 256, 0, stream>>>(deg, rowptr, bsum, N);
    csr_scan2_kernel<<<1, 64, 0, stream>>>(bsum, rowptr, nb, N);
    csr_scan3_kernel<<<nb, 256, 0, stream>>>(rowptr, cursor, bsum, N);
    csr_scatter_kernel<<<(E + 255) / 256, 256, 0, stream>>>(ei, cursor, csr_src, csr_eid, E);

    for (int l = 0; l < 5; ++l) {
        gat_scores_kernel<<<(N + 15) / 16, 256, 0, stream>>>(
            h, W_gat + l * 4096, att_src + l * 64, att_dst + l * 64,
            W_edge + l * 128, att_edge + l * 64, hs, asrc, adst, weae, stats, N);
        gat_edge_kernel<<<(N + 3) / 4, 256, 0, stream>>>(
            rowptr, csr_src, csr_eid, ea, asrc, adst, weae, hs, b_gat + l * 64, go, N);
        ln_stats_kernel<<<2048, 256, 0, stream>>>(go, stats, N * 64);
        ln_apply_kernel<<<(N + 15) / 16, 256, 0, stream>>>(go, stats, ln_g + l * 64, ln_b + l * 64,
                                                           W_fc1, l * 64, h, fc1, N);
    }
    head_kernel<<<(N + 3) / 4, 256, 0, stream>>>(fc1, b_fc1, W_fc2, b_fc2, out, N);
}